// Round 14
// baseline (742.414 us; speedup 1.0000x reference)
//
#include <hip/hip_runtime.h>
#include <math.h>

#define NNODES 50000
#define NPAD 50048  // 782 blocks * 64 rows
#define NEDGES 800000
#define NGRAPH 64
#define NEGS 0.2f
#define BNEPS 1e-5f

typedef _Float16 f16;
typedef f16 f16x2 __attribute__((ext_vector_type(2)));
typedef f16 f16x4 __attribute__((ext_vector_type(4)));
typedef f16 f16x8 __attribute__((ext_vector_type(8)));
typedef float f32x4 __attribute__((ext_vector_type(4)));

// ---------------------------------------------------------------------------
// CSR build: histogram -> 3-phase parallel scan -> scatter (counting sort)
// ---------------------------------------------------------------------------
__global__ void hist_kernel(const int* __restrict__ ei, int* __restrict__ deg,
                            int nE, int n) {
    int i = blockIdx.x * blockDim.x + threadIdx.x;
    int total = nE + n;
    if (i >= total) return;
    int dst = (i < nE) ? ei[nE + i] : (i - nE);
    atomicAdd(&deg[dst], 1);
}

__global__ __launch_bounds__(256) void scan1_kernel(const int* __restrict__ deg,
                                                    int* __restrict__ bsum, int n) {
    __shared__ int s[256];
    int t = threadIdx.x;
    int idx = blockIdx.x * 1024 + t * 4;
    int v = 0;
    if (idx + 3 < n) {
        int4 d = *(const int4*)&deg[idx];
        v = d.x + d.y + d.z + d.w;
    } else {
        for (int j = 0; j < 4; j++) if (idx + j < n) v += deg[idx + j];
    }
    s[t] = v;
    __syncthreads();
    for (int off = 128; off >= 1; off >>= 1) {
        if (t < off) s[t] += s[t + off];
        __syncthreads();
    }
    if (t == 0) bsum[blockIdx.x] = s[0];
}

__global__ __launch_bounds__(64) void scan2_kernel(int* __restrict__ bsum, int nb) {
    int t = threadIdx.x;
    int v = (t < nb) ? bsum[t] : 0;
    for (int off = 1; off < 64; off <<= 1) {
        int u = __shfl_up(v, off, 64);
        if (t >= off) v += u;
    }
    int ex = __shfl_up(v, 1, 64);
    if (t == 0) ex = 0;
    if (t < nb) bsum[t] = ex;
}

__global__ __launch_bounds__(256) void scan3_kernel(const int* __restrict__ deg,
                                                    const int* __restrict__ bsum,
                                                    int* __restrict__ row_ptr,
                                                    int* __restrict__ cursor, int n) {
    __shared__ int s[256];
    int t = threadIdx.x;
    int idx = blockIdx.x * 1024 + t * 4;
    int d[4] = {0, 0, 0, 0};
    if (idx + 3 < n) {
        int4 dv = *(const int4*)&deg[idx];
        d[0] = dv.x; d[1] = dv.y; d[2] = dv.z; d[3] = dv.w;
    } else {
        for (int j = 0; j < 4; j++) if (idx + j < n) d[j] = deg[idx + j];
    }
    s[t] = d[0] + d[1] + d[2] + d[3];
    __syncthreads();
    for (int off = 1; off < 256; off <<= 1) {
        int v = (t >= off) ? s[t - off] : 0;
        __syncthreads();
        s[t] += v;
        __syncthreads();
    }
    int prefix = bsum[blockIdx.x] + ((t == 0) ? 0 : s[t - 1]);
    for (int j = 0; j < 4; j++) {
        if (idx + j < n) {
            row_ptr[idx + j] = prefix;
            cursor[idx + j] = prefix;
            prefix += d[j];
        }
    }
    if (idx < n && idx + 4 >= n) row_ptr[n] = prefix;
}

__global__ void scatter_kernel(const int* __restrict__ ei, int* __restrict__ cursor,
                               int* __restrict__ col, int nE, int n) {
    int i = blockIdx.x * blockDim.x + threadIdx.x;
    int total = nE + n;
    if (i >= total) return;
    int src, dst;
    if (i < nE) { src = ei[i]; dst = ei[nE + i]; }
    else        { src = i - nE; dst = src; }
    int pos = atomicAdd(&cursor[dst], 1);
    col[pos] = src;
}

// Wave-per-node stable rank sort (bit-identical ordering to insertion sort).
__global__ __launch_bounds__(256) void sortadj_kernel(const int* __restrict__ row_ptr,
                                                      int* __restrict__ col, int n) {
    int wv = threadIdx.x >> 6;
    int lane = threadIdx.x & 63;
    int i = (blockIdx.x << 2) + wv;
    if (i >= n) return;
    int lo = row_ptr[i], hi = row_ptr[i + 1];
    int d = hi - lo;
    if (d <= 1) return;
    if (d <= 64) {
        int v = (lane < d) ? col[lo + lane] : 0x7fffffff;
        int rank = 0;
        for (int j = 0; j < d; j++) {
            int u = __shfl(v, j, 64);
            rank += (u < v) || (u == v && j < lane);
        }
        if (lane < d) col[lo + rank] = v;
    } else if (lane == 0) {
        for (int a = lo + 1; a < hi; a++) {
            int v = col[a];
            int b = a - 1;
            while (b >= lo && col[b] > v) { col[b + 1] = col[b]; b--; }
            col[b + 1] = v;
        }
    }
}

// ---------------------------------------------------------------------------
// One-shot prep: x fp32->fp16 + pack all 3 weight pairs into MFMA B order.
// ---------------------------------------------------------------------------
__device__ __forceinline__ void packB_one(const float* __restrict__ Wl,
                                          const float* __restrict__ Wr,
                                          f16* __restrict__ Bp, int K, int M,
                                          int idx) {
    int k = idx / (2 * M);
    int nn = idx % (2 * M);
    float v = (nn < M) ? Wl[k * M + nn] : Wr[k * M + (nn - M)];
    int NCG = (2 * M) / 256;
    int ks = k >> 5;
    int quad = (k >> 3) & 3;
    int j = k & 7;
    int lane = quad * 16 + (nn & 15);
    int cg = nn >> 8;
    int tl = (nn >> 4) & 15;
    Bp[((((size_t)ks * NCG + cg) * 16 + tl) * 64 + lane) * 8 + j] = (f16)v;
}

__global__ void prep_kernel(const float* __restrict__ x, f16* __restrict__ xh,
                            const float* __restrict__ Wl0, const float* __restrict__ Wr0,
                            f16* __restrict__ Bp0,
                            const float* __restrict__ Wl1, const float* __restrict__ Wr1,
                            f16* __restrict__ Bp1,
                            const float* __restrict__ Wl2, const float* __restrict__ Wr2,
                            f16* __restrict__ Bp2) {
    int idx = blockIdx.x * blockDim.x + threadIdx.x;
    int cvtN = NNODES * 128 / 4;
    if (idx < cvtN) {
        float4 v = ((const float4*)x)[idx];
        f16x4 o; o.x = (f16)v.x; o.y = (f16)v.y; o.z = (f16)v.z; o.w = (f16)v.w;
        ((f16x4*)xh)[idx] = o;
        return;
    }
    idx -= cvtN;
    if (idx < 128 * 512) { packB_one(Wl0, Wr0, Bp0, 128, 256, idx); return; }
    idx -= 128 * 512;
    if (idx < 256 * 512) { packB_one(Wl1, Wr1, Bp1, 256, 256, idx); return; }
    idx -= 256 * 512;
    if (idx < 256 * 256) { packB_one(Wl2, Wr2, Bp2, 256, 128, idx); }
}

// ---------------------------------------------------------------------------
// MFMA dual-GEMM (R12 version — reverted from the 2-row-tile experiment that
// regressed 37us by cutting occupancy): 64 rows/block, double-buffered B slab,
// raw s_barrier, vmcnt(4) gating, 4 blocks/CU.
// ---------------------------------------------------------------------------
__device__ __forceinline__ void dma16h(const f16* g, f16* l) {
    __builtin_amdgcn_global_load_lds(
        (const __attribute__((address_space(1))) void*)g,
        (__attribute__((address_space(3))) void*)l, 16, 0, 0);
}

template <int K, int M>
__global__ __launch_bounds__(256, 4) void gemm_mfma_kernel(
    const f16* __restrict__ A, const f16* __restrict__ Bp,
    const float* __restrict__ bl, const float* __restrict__ br,
    f16* __restrict__ xlh, f16* __restrict__ xrh, int n) {
    constexpr int KS = K / 32;
    constexpr int NCG = (2 * M) / 256;
    constexpr int TILES = 16;
    __shared__ __align__(16) f16 ldsB[2][8192];

    int w = threadIdx.x >> 6;
    int lane = threadIdx.x & 63;
    int row0 = blockIdx.x * 64 + w * 16;
    int cg = blockIdx.y;
    int col0 = cg * 256;
    int quad = lane >> 4;

    const f16* Arow = A + (size_t)(row0 + (lane & 15)) * K + quad * 8;
    f16x8 av[KS];
#pragma unroll
    for (int ks = 0; ks < KS; ks++) av[ks] = *(const f16x8*)(Arow + ks * 32);

    f32x4 acc[TILES];
#pragma unroll
    for (int t = 0; t < TILES; t++) acc[t] = (f32x4){0.f, 0.f, 0.f, 0.f};

    auto issueB = [&](int ks) {
        size_t slab = ((size_t)ks * NCG + cg) * 8192;
        f16* dst = &ldsB[ks & 1][0];
#pragma unroll
        for (int d = 0; d < 4; d++) {
            int tl = w * 4 + d;
            dma16h(Bp + slab + tl * 512 + lane * 8, dst + tl * 512);
        }
    };

    issueB(0);
    for (int ks = 0; ks < KS; ks++) {
        if (ks + 1 < KS) {
            issueB(ks + 1);
            asm volatile("s_waitcnt vmcnt(4)" ::: "memory");
        } else {
            asm volatile("s_waitcnt vmcnt(0)" ::: "memory");
        }
        asm volatile("s_barrier" ::: "memory");
        const f16* lb = &ldsB[ks & 1][0];
#pragma unroll
        for (int t = 0; t < TILES; t++) {
            f16x8 bv = *(const f16x8*)(lb + t * 512 + lane * 8);
            acc[t] = __builtin_amdgcn_mfma_f32_16x16x32_f16(av[ks], bv, acc[t], 0, 0, 0);
        }
        asm volatile("s_waitcnt lgkmcnt(0)" ::: "memory");
        asm volatile("s_barrier" ::: "memory");
    }

    int rq = quad * 4;
#pragma unroll
    for (int t = 0; t < TILES; t++) {
        int c = col0 + t * 16 + (lane & 15);
        float bias = (c < M) ? bl[c] : br[c - M];
#pragma unroll
        for (int r = 0; r < 4; r++) {
            int row = row0 + rq + r;
            if (row < n) {
                float v = acc[t][r] + bias;
                if (c < M) xlh[(size_t)row * M + c] = (f16)v;
                else       xrh[(size_t)row * M + (c - M)] = (f16)v;
            }
        }
    }
}

// ---------------------------------------------------------------------------
// GATv2 aggregation: one wave per dst node; fp16 xl via async DMA,
// double-buffered LDS, B=8 edges/batch (amortize fixed per-batch overhead:
// aggs measured ~126 wave-inst/edge vs ~40 in the loop body), packed-f16
// score path; xr fp16 in memory. Accumulation order unchanged (ascending
// edge index) -> bit-identical output.
// ---------------------------------------------------------------------------
template <int H, int C, bool ELU, bool OUTH>
__global__ __launch_bounds__(256) void gat_agg_kernel(
    const f16* __restrict__ xlh, const f16* __restrict__ xrh,
    const float* __restrict__ att, const float* __restrict__ cb,
    const float* __restrict__ bn_g, const float* __restrict__ bn_b,
    const float* __restrict__ bn_m, const float* __restrict__ bn_v,
    const int* __restrict__ row_ptr, const int* __restrict__ col_idx,
    f16* __restrict__ outh, float* __restrict__ outf, int n) {
    constexpr int M = H * C;          // 256 or 128
    constexpr int VPL = M / 64;       // 4 or 2
    constexpr int NP = VPL / 2;       // f16x2 pairs per lane
    constexpr int EPD = 512 / M;      // edges per 1KB DMA: 2 or 4
    constexpr int B = 8;              // edges per batch
    constexpr int NDMA = B / EPD;     // DMAs per batch: 4 or 2
    constexpr int BUFH = NDMA * 512;  // halves per buffer

    __shared__ __align__(16) f16 lds[4][2][BUFH];

    int wv = threadIdx.x >> 6;
    int lane = threadIdx.x & 63;
    int wid = (blockIdx.x << 2) + wv;
    if (wid >= n) return;
    const int i = __builtin_amdgcn_readfirstlane(wid);
    const int base = lane * VPL;

    f16x2 xr2[NP], at2[NP];
    float acc[VPL];
#pragma unroll
    for (int p = 0; p < NP; p++) {
        xr2[p] = *(const f16x2*)(xrh + (size_t)i * M + base + 2 * p);
        at2[p].x = (f16)att[base + 2 * p];
        at2[p].y = (f16)att[base + 2 * p + 1];
    }
#pragma unroll
    for (int j = 0; j < VPL; j++) acc[j] = 0.f;
    float den = 0.f;

    f16x2 z2; z2.x = (f16)0.f; z2.y = (f16)0.f;
    f16x2 ns2; ns2.x = (f16)NEGS; ns2.y = (f16)NEGS;

    const int e0 = __builtin_amdgcn_readfirstlane(row_ptr[i]);
    const int e1 = __builtin_amdgcn_readfirstlane(row_ptr[i + 1]);
    const int nb = (e1 - e0 + B - 1) / B;
    const int elast = e1 - 1;  // deg >= 1 always (self-loop)

    int nxt[B];
    auto loadcols = [&](int kk) {
#pragma unroll
        for (int b = 0; b < B; b++) {
            int idx = e0 + kk * B + b;
            nxt[b] = col_idx[min(idx, elast)];
        }
    };
    auto issue = [&](int buf) {
        f16* lbase = &lds[wv][buf][0];
#pragma unroll
        for (int d = 0; d < NDMA; d++) {
            int sel = (EPD == 2) ? (lane >> 5) : (lane >> 4);
            int r = nxt[EPD * d + sel];
            const f16* g = xlh + (size_t)r * M + ((lane & (64 / EPD - 1)) << 3);
            dma16h(g, lbase + d * 512);
        }
    };

    loadcols(0);
    issue(0);
    if (nb > 1) loadcols(1);

    for (int k = 0; k < nb; k++) {
        bool more = (k + 1 < nb);
        if (more) {
            issue((k + 1) & 1);
            if (NDMA == 4)
                asm volatile("s_waitcnt vmcnt(4)" ::: "memory");
            else
                asm volatile("s_waitcnt vmcnt(2)" ::: "memory");
        } else {
            asm volatile("s_waitcnt vmcnt(0)" ::: "memory");
        }
        if (k + 2 < nb) loadcols(k + 2);

        const f16* lb = &lds[wv][k & 1][0];
        const int ebase = e0 + k * B;
        f16x4 xv4[B];
        float sc[B];
#pragma unroll
        for (int b = 0; b < B; b++) {
            const f16* rowp = (EPD == 2)
                ? lb + (b >> 1) * 512 + (b & 1) * 256 + lane * 4
                : lb + (b >> 2) * 512 + (b & 3) * 128 + lane * 2;
            if (VPL == 4) {
                xv4[b] = *(const f16x4*)rowp;
            } else {
                f16x2 t = *(const f16x2*)rowp;
                xv4[b].x = t.x; xv4[b].y = t.y;
            }
            float s = 0.f;
#pragma unroll
            for (int p = 0; p < NP; p++) {
                f16x2 xp;
                xp.x = (p == 0) ? xv4[b].x : xv4[b].z;
                xp.y = (p == 0) ? xv4[b].y : xv4[b].w;
                f16x2 t = xp + xr2[p];
                f16x2 lk = __builtin_elementwise_max(t, z2) +
                           ns2 * __builtin_elementwise_min(t, z2);
                s = __builtin_amdgcn_fdot2(lk, at2[p], s, false);
            }
            sc[b] = s;
        }
        constexpr int RED = (H == 4) ? 8 : 32;
#pragma unroll
        for (int off = 1; off <= RED; off <<= 1)
#pragma unroll
            for (int b = 0; b < B; b++) sc[b] += __shfl_xor(sc[b], off, 64);
#pragma unroll
        for (int b = 0; b < B; b++) {
            float w = (ebase + b < e1) ? __expf(sc[b]) : 0.f;
            den += w;
            acc[0] += w * (float)xv4[b].x;
            acc[1] += w * (float)xv4[b].y;
            if (VPL == 4) {
                acc[2] += w * (float)xv4[b].z;
                acc[3] += w * (float)xv4[b].w;
            }
        }
    }

    float inv = 1.0f / den;
    float ov[VPL];
#pragma unroll
    for (int j = 0; j < VPL; j++) {
        int hc = base + j;
        float val = acc[j] * inv + cb[hc];
        val = (val - bn_m[hc]) * bn_g[hc] / sqrtf(bn_v[hc] + BNEPS) + bn_b[hc];
        if (ELU) val = (val > 0.f) ? val : expm1f(val);
        ov[j] = val;
    }
    if (OUTH) {
        f16* op = outh + (size_t)i * M + base;
        if (VPL == 4) {
            f16x4 v; v.x = (f16)ov[0]; v.y = (f16)ov[1];
            v.z = (f16)ov[2]; v.w = (f16)ov[3];
            *(f16x4*)op = v;
        } else {
            f16x2 v; v.x = (f16)ov[0]; v.y = (f16)ov[1];
            *(f16x2*)op = v;
        }
    } else {
        float* op = outf + (size_t)i * M + base;
        if (VPL == 4) {
            float4 v; v.x = ov[0]; v.y = ov[1]; v.z = ov[2]; v.w = ov[3];
            *(float4*)op = v;
        } else {
            float2 v; v.x = ov[0]; v.y = ov[1];
            *(float2*)op = v;
        }
    }
}

// ---------------------------------------------------------------------------
// Graph pooling without atomics (batch[] sorted -> contiguous ranges)
// ---------------------------------------------------------------------------
__device__ __forceinline__ int lower_bound_i(const int* a, int n, int v) {
    int lo = 0, hi = n;
    while (lo < hi) {
        int m = (lo + hi) >> 1;
        if (a[m] < v) lo = m + 1; else hi = m;
    }
    return lo;
}

__global__ __launch_bounds__(512) void pool_kernel(
    const float* __restrict__ h, const int* __restrict__ batch,
    float* __restrict__ sum_out, float* __restrict__ max_out,
    float* __restrict__ cnt, int n) {
    int g = blockIdx.x;
    int tid = threadIdx.x;
    int ch = tid & 127;
    int r = tid >> 7;

    int lo = lower_bound_i(batch, n, g);
    int hi = lower_bound_i(batch, n, g + 1);

    float sum = 0.f, mx = -INFINITY;
    for (int i = lo + r; i < hi; i += 4) {
        float v = h[(size_t)i * 128 + ch];
        sum += v;
        mx = fmaxf(mx, v);
    }
    __shared__ float ssum[512], smax[512];
    ssum[tid] = sum; smax[tid] = mx;
    __syncthreads();
    if (r == 0) {
        sum = ssum[ch] + ssum[128 + ch] + ssum[256 + ch] + ssum[384 + ch];
        mx = fmaxf(fmaxf(smax[ch], smax[128 + ch]),
                   fmaxf(smax[256 + ch], smax[384 + ch]));
        sum_out[g * 128 + ch] = sum;
        max_out[g * 128 + ch] = mx;
        if (ch == 0) cnt[g] = (float)(hi - lo);
    }
}

// ---------------------------------------------------------------------------
// Classifier MLP: one block (128 threads) per graph. 256->128->64->1
// ---------------------------------------------------------------------------
__global__ __launch_bounds__(128) void mlp_kernel(
    const float* __restrict__ sum_in, const float* __restrict__ max_in,
    const float* __restrict__ cnt, const float* __restrict__ cw0,
    const float* __restrict__ cb0, const float* __restrict__ cw1,
    const float* __restrict__ cb1, const float* __restrict__ cw2,
    const float* __restrict__ cb2, float* __restrict__ out) {
    int g = blockIdx.x;
    int t = threadIdx.x;
    __shared__ float z[256];
    __shared__ float z1[128];

    float c = cnt[g];
    float inv = 1.0f / fmaxf(c, 1.0f);
    z[t] = sum_in[g * 128 + t] * inv;
    float mx = max_in[g * 128 + t];
    if (!isfinite(mx)) mx = 0.f;
    z[128 + t] = mx;
    __syncthreads();

    float a = cb0[t];
    for (int k = 0; k < 256; k++) a += z[k] * cw0[k * 128 + t];
    z1[t] = fmaxf(a, 0.f);
    __syncthreads();

    if (t < 64) {
        float b = cb1[t];
        for (int k = 0; k < 128; k++) b += z1[k] * cw1[k * 64 + t];
        float p = fmaxf(b, 0.f) * cw2[t];
#pragma unroll
        for (int off = 32; off >= 1; off >>= 1) p += __shfl_xor(p, off, 64);
        if (t == 0) out[g] = p + cb2[0];
    }
}

// ---------------------------------------------------------------------------
extern "C" void kernel_launch(void* const* d_in, const int* in_sizes, int n_in,
                              void* d_out, int out_size, void* d_ws, size_t ws_size,
                              hipStream_t stream) {
    const float* x = (const float*)d_in[0];
    const int* ei = (const int*)d_in[1];
    const int* batch = (const int*)d_in[2];
    const float* Wl0 = (const float*)d_in[3];
    const float* bl0 = (const float*)d_in[4];
    const float* Wr0 = (const float*)d_in[5];
    const float* br0 = (const float*)d_in[6];
    const float* a0 = (const float*)d_in[7];
    const float* c0 = (const float*)d_in[8];
    const float* Wl1 = (const float*)d_in[9];
    const float* bl1 = (const float*)d_in[10];
    const float* Wr1 = (const float*)d_in[11];
    const float* br1 = (const float*)d_in[12];
    const float* a1 = (const float*)d_in[13];
    const float* c1 = (const float*)d_in[14];
    const float* Wl2 = (const float*)d_in[15];
    const float* bl2 = (const float*)d_in[16];
    const float* Wr2 = (const float*)d_in[17];
    const float* br2 = (const float*)d_in[18];
    const float* a2 = (const float*)d_in[19];
    const float* c2 = (const float*)d_in[20];
    const float* g0 = (const float*)d_in[21];
    const float* be0 = (const float*)d_in[22];
    const float* m0 = (const float*)d_in[23];
    const float* v0 = (const float*)d_in[24];
    const float* g1 = (const float*)d_in[25];
    const float* be1 = (const float*)d_in[26];
    const float* m1 = (const float*)d_in[27];
    const float* v1 = (const float*)d_in[28];
    const float* g2 = (const float*)d_in[29];
    const float* be2 = (const float*)d_in[30];
    const float* m2 = (const float*)d_in[31];
    const float* v2 = (const float*)d_in[32];
    const float* cw0 = (const float*)d_in[33];
    const float* cb0 = (const float*)d_in[34];
    const float* cw1 = (const float*)d_in[35];
    const float* cb1 = (const float*)d_in[36];
    const float* cw2 = (const float*)d_in[37];
    const float* cb2 = (const float*)d_in[38];
    float* out = (float*)d_out;

    const int N = NNODES, E = NEDGES, G = NGRAPH;
    char* ws = (char*)d_ws;
    size_t off = 0;
    auto alloc = [&](size_t bytes) -> void* {
        void* p = ws + off;
        off += (bytes + 255) & ~(size_t)255;
        return p;
    };
    f16* xh = (f16*)alloc((size_t)NPAD * 128 * 2);      // x as fp16
    f16* h16 = (f16*)alloc((size_t)NPAD * 256 * 2);     // inter-layer h fp16
    f16* xlh = (f16*)alloc((size_t)NPAD * 256 * 2);     // gathered operand
    f16* xrh = (f16*)alloc((size_t)NPAD * 256 * 2);     // per-dst operand fp16
    float* h2 = (float*)alloc((size_t)N * 128 * 4);     // L2 agg out (pool in)
    f16* Bp0 = (f16*)alloc((size_t)128 * 512 * 2);
    f16* Bp1 = (f16*)alloc((size_t)256 * 512 * 2);
    f16* Bp2 = (f16*)alloc((size_t)256 * 256 * 2);
    int* deg = (int*)alloc((size_t)N * 4);
    int* row_ptr = (int*)alloc((size_t)(N + 1) * 4);
    int* cursor = (int*)alloc((size_t)N * 4);
    int* col_idx = (int*)alloc((size_t)(E + N) * 4);
    int* bsum = (int*)alloc((size_t)64 * 4);
    float* mean_acc = (float*)alloc((size_t)G * 128 * 4);
    float* gmax_f = (float*)alloc((size_t)G * 128 * 4);
    float* cnt = (float*)alloc((size_t)G * 4);
    (void)ws_size; (void)n_in; (void)in_sizes; (void)out_size;

    hipMemsetAsync(deg, 0, (size_t)N * 4, stream);

    int totE = E + N;
    int ntiles = (N + 1023) / 1024;  // 49
    hist_kernel<<<(totE + 255) / 256, 256, 0, stream>>>(ei, deg, E, N);
    scan1_kernel<<<ntiles, 256, 0, stream>>>(deg, bsum, N);
    scan2_kernel<<<1, 64, 0, stream>>>(bsum, ntiles);
    scan3_kernel<<<ntiles, 256, 0, stream>>>(deg, bsum, row_ptr, cursor, N);
    scatter_kernel<<<(totE + 255) / 256, 256, 0, stream>>>(ei, cursor, col_idx, E, N);
    sortadj_kernel<<<(N + 3) / 4, 256, 0, stream>>>(row_ptr, col_idx, N);

    // one-shot prep: cvt + all 3 weight packs
    int prepN = N * 128 / 4 + 128 * 512 + 256 * 512 + 256 * 256;
    prep_kernel<<<(prepN + 255) / 256, 256, 0, stream>>>(
        x, xh, Wl0, Wr0, Bp0, Wl1, Wr1, Bp1, Wl2, Wr2, Bp2);

    int gblocks = NPAD / 64;              // 782
    int agg_grid = (N + 3) / 4;

    // Layer 0: 128 -> 4x64, ELU(BN(.)), h16 out
    gemm_mfma_kernel<128, 256><<<dim3(gblocks, 2), 256, 0, stream>>>(
        xh, Bp0, bl0, br0, xlh, xrh, N);
    gat_agg_kernel<4, 64, true, true><<<agg_grid, 256, 0, stream>>>(
        xlh, xrh, a0, c0, g0, be0, m0, v0, row_ptr, col_idx, h16, nullptr, N);

    // Layer 1: 256 -> 4x64, ELU(BN(.)), h16 out
    gemm_mfma_kernel<256, 256><<<dim3(gblocks, 2), 256, 0, stream>>>(
        h16, Bp1, bl1, br1, xlh, xrh, N);
    gat_agg_kernel<4, 64, true, true><<<agg_grid, 256, 0, stream>>>(
        xlh, xrh, a1, c1, g1, be1, m1, v1, row_ptr, col_idx, h16, nullptr, N);

    // Layer 2: 256 -> 1x128, BN only, fp32 out for pooling
    gemm_mfma_kernel<256, 128><<<dim3(gblocks, 1), 256, 0, stream>>>(
        h16, Bp2, bl2, br2, xlh, xrh, N);
    gat_agg_kernel<1, 128, false, false><<<agg_grid, 256, 0, stream>>>(
        xlh, xrh, a2, c2, g2, be2, m2, v2, row_ptr, col_idx, nullptr, h2, N);

    pool_kernel<<<G, 512, 0, stream>>>(h2, batch, mean_acc, gmax_f, cnt, N);
    mlp_kernel<<<G, 128, 0, stream>>>(mean_acc, gmax_f, cnt, cw0, cb0, cw1, cb1, cw2, cb2, out);
}

// Round 15
// 676.490 us; speedup vs baseline: 1.0975x; 1.0975x over previous
//
#include <hip/hip_runtime.h>
#include <math.h>

#define NNODES 50000
#define NPAD 50048  // 782 blocks * 64 rows
#define NEDGES 800000
#define NGRAPH 64
#define NEGS 0.2f
#define BNEPS 1e-5f

typedef _Float16 f16;
typedef f16 f16x2 __attribute__((ext_vector_type(2)));
typedef f16 f16x4 __attribute__((ext_vector_type(4)));
typedef f16 f16x8 __attribute__((ext_vector_type(8)));
typedef float f32x4 __attribute__((ext_vector_type(4)));

// ---------------------------------------------------------------------------
// CSR build: histogram -> 3-phase parallel scan -> scatter (counting sort)
// ---------------------------------------------------------------------------
__global__ void hist_kernel(const int* __restrict__ ei, int* __restrict__ deg,
                            int nE, int n) {
    int i = blockIdx.x * blockDim.x + threadIdx.x;
    int total = nE + n;
    if (i >= total) return;
    int dst = (i < nE) ? ei[nE + i] : (i - nE);
    atomicAdd(&deg[dst], 1);
}

__global__ __launch_bounds__(256) void scan1_kernel(const int* __restrict__ deg,
                                                    int* __restrict__ bsum, int n) {
    __shared__ int s[256];
    int t = threadIdx.x;
    int idx = blockIdx.x * 1024 + t * 4;
    int v = 0;
    if (idx + 3 < n) {
        int4 d = *(const int4*)&deg[idx];
        v = d.x + d.y + d.z + d.w;
    } else {
        for (int j = 0; j < 4; j++) if (idx + j < n) v += deg[idx + j];
    }
    s[t] = v;
    __syncthreads();
    for (int off = 128; off >= 1; off >>= 1) {
        if (t < off) s[t] += s[t + off];
        __syncthreads();
    }
    if (t == 0) bsum[blockIdx.x] = s[0];
}

__global__ __launch_bounds__(64) void scan2_kernel(int* __restrict__ bsum, int nb) {
    int t = threadIdx.x;
    int v = (t < nb) ? bsum[t] : 0;
    for (int off = 1; off < 64; off <<= 1) {
        int u = __shfl_up(v, off, 64);
        if (t >= off) v += u;
    }
    int ex = __shfl_up(v, 1, 64);
    if (t == 0) ex = 0;
    if (t < nb) bsum[t] = ex;
}

__global__ __launch_bounds__(256) void scan3_kernel(const int* __restrict__ deg,
                                                    const int* __restrict__ bsum,
                                                    int* __restrict__ row_ptr,
                                                    int* __restrict__ cursor, int n) {
    __shared__ int s[256];
    int t = threadIdx.x;
    int idx = blockIdx.x * 1024 + t * 4;
    int d[4] = {0, 0, 0, 0};
    if (idx + 3 < n) {
        int4 dv = *(const int4*)&deg[idx];
        d[0] = dv.x; d[1] = dv.y; d[2] = dv.z; d[3] = dv.w;
    } else {
        for (int j = 0; j < 4; j++) if (idx + j < n) d[j] = deg[idx + j];
    }
    s[t] = d[0] + d[1] + d[2] + d[3];
    __syncthreads();
    for (int off = 1; off < 256; off <<= 1) {
        int v = (t >= off) ? s[t - off] : 0;
        __syncthreads();
        s[t] += v;
        __syncthreads();
    }
    int prefix = bsum[blockIdx.x] + ((t == 0) ? 0 : s[t - 1]);
    for (int j = 0; j < 4; j++) {
        if (idx + j < n) {
            row_ptr[idx + j] = prefix;
            cursor[idx + j] = prefix;
            prefix += d[j];
        }
    }
    if (idx < n && idx + 4 >= n) row_ptr[n] = prefix;
}

__global__ void scatter_kernel(const int* __restrict__ ei, int* __restrict__ cursor,
                               int* __restrict__ col, int nE, int n) {
    int i = blockIdx.x * blockDim.x + threadIdx.x;
    int total = nE + n;
    if (i >= total) return;
    int src, dst;
    if (i < nE) { src = ei[i]; dst = ei[nE + i]; }
    else        { src = i - nE; dst = src; }
    int pos = atomicAdd(&cursor[dst], 1);
    col[pos] = src;
}

// Wave-per-node stable rank sort (bit-identical ordering to insertion sort).
__global__ __launch_bounds__(256) void sortadj_kernel(const int* __restrict__ row_ptr,
                                                      int* __restrict__ col, int n) {
    int wv = threadIdx.x >> 6;
    int lane = threadIdx.x & 63;
    int i = (blockIdx.x << 2) + wv;
    if (i >= n) return;
    int lo = row_ptr[i], hi = row_ptr[i + 1];
    int d = hi - lo;
    if (d <= 1) return;
    if (d <= 64) {
        int v = (lane < d) ? col[lo + lane] : 0x7fffffff;
        int rank = 0;
        for (int j = 0; j < d; j++) {
            int u = __shfl(v, j, 64);
            rank += (u < v) || (u == v && j < lane);
        }
        if (lane < d) col[lo + rank] = v;
    } else if (lane == 0) {
        for (int a = lo + 1; a < hi; a++) {
            int v = col[a];
            int b = a - 1;
            while (b >= lo && col[b] > v) { col[b + 1] = col[b]; b--; }
            col[b + 1] = v;
        }
    }
}

// ---------------------------------------------------------------------------
// One-shot prep: x fp32->fp16 + pack all 3 weight pairs into MFMA B order.
// ---------------------------------------------------------------------------
__device__ __forceinline__ void packB_one(const float* __restrict__ Wl,
                                          const float* __restrict__ Wr,
                                          f16* __restrict__ Bp, int K, int M,
                                          int idx) {
    int k = idx / (2 * M);
    int nn = idx % (2 * M);
    float v = (nn < M) ? Wl[k * M + nn] : Wr[k * M + (nn - M)];
    int NCG = (2 * M) / 256;
    int ks = k >> 5;
    int quad = (k >> 3) & 3;
    int j = k & 7;
    int lane = quad * 16 + (nn & 15);
    int cg = nn >> 8;
    int tl = (nn >> 4) & 15;
    Bp[((((size_t)ks * NCG + cg) * 16 + tl) * 64 + lane) * 8 + j] = (f16)v;
}

__global__ void prep_kernel(const float* __restrict__ x, f16* __restrict__ xh,
                            const float* __restrict__ Wl0, const float* __restrict__ Wr0,
                            f16* __restrict__ Bp0,
                            const float* __restrict__ Wl1, const float* __restrict__ Wr1,
                            f16* __restrict__ Bp1,
                            const float* __restrict__ Wl2, const float* __restrict__ Wr2,
                            f16* __restrict__ Bp2) {
    int idx = blockIdx.x * blockDim.x + threadIdx.x;
    int cvtN = NNODES * 128 / 4;
    if (idx < cvtN) {
        float4 v = ((const float4*)x)[idx];
        f16x4 o; o.x = (f16)v.x; o.y = (f16)v.y; o.z = (f16)v.z; o.w = (f16)v.w;
        ((f16x4*)xh)[idx] = o;
        return;
    }
    idx -= cvtN;
    if (idx < 128 * 512) { packB_one(Wl0, Wr0, Bp0, 128, 256, idx); return; }
    idx -= 128 * 512;
    if (idx < 256 * 512) { packB_one(Wl1, Wr1, Bp1, 256, 256, idx); return; }
    idx -= 256 * 512;
    if (idx < 256 * 256) { packB_one(Wl2, Wr2, Bp2, 256, 128, idx); }
}

// ---------------------------------------------------------------------------
// MFMA dual-GEMM (R12 config — best measured): 64 rows/block, double-buffered
// B slab, raw s_barrier, vmcnt(4) gating, 4 blocks/CU.
// NOTE: 2-row-tile variant (R13) regressed 37us (occupancy 4->2 blocks/CU).
// ---------------------------------------------------------------------------
__device__ __forceinline__ void dma16h(const f16* g, f16* l) {
    __builtin_amdgcn_global_load_lds(
        (const __attribute__((address_space(1))) void*)g,
        (__attribute__((address_space(3))) void*)l, 16, 0, 0);
}

template <int K, int M>
__global__ __launch_bounds__(256, 4) void gemm_mfma_kernel(
    const f16* __restrict__ A, const f16* __restrict__ Bp,
    const float* __restrict__ bl, const float* __restrict__ br,
    f16* __restrict__ xlh, f16* __restrict__ xrh, int n) {
    constexpr int KS = K / 32;
    constexpr int NCG = (2 * M) / 256;
    constexpr int TILES = 16;
    __shared__ __align__(16) f16 ldsB[2][8192];

    int w = threadIdx.x >> 6;
    int lane = threadIdx.x & 63;
    int row0 = blockIdx.x * 64 + w * 16;
    int cg = blockIdx.y;
    int col0 = cg * 256;
    int quad = lane >> 4;

    const f16* Arow = A + (size_t)(row0 + (lane & 15)) * K + quad * 8;
    f16x8 av[KS];
#pragma unroll
    for (int ks = 0; ks < KS; ks++) av[ks] = *(const f16x8*)(Arow + ks * 32);

    f32x4 acc[TILES];
#pragma unroll
    for (int t = 0; t < TILES; t++) acc[t] = (f32x4){0.f, 0.f, 0.f, 0.f};

    auto issueB = [&](int ks) {
        size_t slab = ((size_t)ks * NCG + cg) * 8192;
        f16* dst = &ldsB[ks & 1][0];
#pragma unroll
        for (int d = 0; d < 4; d++) {
            int tl = w * 4 + d;
            dma16h(Bp + slab + tl * 512 + lane * 8, dst + tl * 512);
        }
    };

    issueB(0);
    for (int ks = 0; ks < KS; ks++) {
        if (ks + 1 < KS) {
            issueB(ks + 1);
            asm volatile("s_waitcnt vmcnt(4)" ::: "memory");
        } else {
            asm volatile("s_waitcnt vmcnt(0)" ::: "memory");
        }
        asm volatile("s_barrier" ::: "memory");
        const f16* lb = &ldsB[ks & 1][0];
#pragma unroll
        for (int t = 0; t < TILES; t++) {
            f16x8 bv = *(const f16x8*)(lb + t * 512 + lane * 8);
            acc[t] = __builtin_amdgcn_mfma_f32_16x16x32_f16(av[ks], bv, acc[t], 0, 0, 0);
        }
        asm volatile("s_waitcnt lgkmcnt(0)" ::: "memory");
        asm volatile("s_barrier" ::: "memory");
    }

    int rq = quad * 4;
#pragma unroll
    for (int t = 0; t < TILES; t++) {
        int c = col0 + t * 16 + (lane & 15);
        float bias = (c < M) ? bl[c] : br[c - M];
#pragma unroll
        for (int r = 0; r < 4; r++) {
            int row = row0 + rq + r;
            if (row < n) {
                float v = acc[t][r] + bias;
                if (c < M) xlh[(size_t)row * M + c] = (f16)v;
                else       xrh[(size_t)row * M + (c - M)] = (f16)v;
            }
        }
    }
}

// ---------------------------------------------------------------------------
// GATv2 aggregation (R12 config — best measured): one wave per dst node,
// fp16 xl via async DMA, double-buffered LDS, B=4 edges/batch (16 KB/block,
// ~69% occupancy), packed-f16 score path; xr fp16 in memory.
// NOTE: B=8 (R14) regressed 30us/dispatch (32 KB LDS -> occupancy 36%).
// ---------------------------------------------------------------------------
template <int H, int C, bool ELU, bool OUTH>
__global__ __launch_bounds__(256) void gat_agg_kernel(
    const f16* __restrict__ xlh, const f16* __restrict__ xrh,
    const float* __restrict__ att, const float* __restrict__ cb,
    const float* __restrict__ bn_g, const float* __restrict__ bn_b,
    const float* __restrict__ bn_m, const float* __restrict__ bn_v,
    const int* __restrict__ row_ptr, const int* __restrict__ col_idx,
    f16* __restrict__ outh, float* __restrict__ outf, int n) {
    constexpr int M = H * C;          // 256 or 128
    constexpr int VPL = M / 64;       // 4 or 2
    constexpr int NP = VPL / 2;       // f16x2 pairs per lane
    constexpr int EPD = 512 / M;      // edges per 1KB DMA: 2 or 4
    constexpr int B = 4;              // edges per batch
    constexpr int NDMA = B / EPD;     // DMAs per batch: 2 or 1
    constexpr int BUFH = NDMA * 512;

    __shared__ __align__(16) f16 lds[4][2][BUFH];

    int wv = threadIdx.x >> 6;
    int lane = threadIdx.x & 63;
    int wid = (blockIdx.x << 2) + wv;
    if (wid >= n) return;
    const int i = __builtin_amdgcn_readfirstlane(wid);
    const int base = lane * VPL;

    f16x2 xr2[NP], at2[NP];
    float acc[VPL];
#pragma unroll
    for (int p = 0; p < NP; p++) {
        xr2[p] = *(const f16x2*)(xrh + (size_t)i * M + base + 2 * p);
        at2[p].x = (f16)att[base + 2 * p];
        at2[p].y = (f16)att[base + 2 * p + 1];
    }
#pragma unroll
    for (int j = 0; j < VPL; j++) acc[j] = 0.f;
    float den = 0.f;

    f16x2 z2; z2.x = (f16)0.f; z2.y = (f16)0.f;
    f16x2 ns2; ns2.x = (f16)NEGS; ns2.y = (f16)NEGS;

    const int e0 = __builtin_amdgcn_readfirstlane(row_ptr[i]);
    const int e1 = __builtin_amdgcn_readfirstlane(row_ptr[i + 1]);
    const int nb = (e1 - e0 + B - 1) / B;
    const int elast = e1 - 1;  // deg >= 1 always (self-loop)

    int nxt[B];
    auto loadcols = [&](int kk) {
#pragma unroll
        for (int b = 0; b < B; b++) {
            int idx = e0 + kk * B + b;
            nxt[b] = col_idx[min(idx, elast)];
        }
    };
    auto issue = [&](int buf) {
        f16* lbase = &lds[wv][buf][0];
#pragma unroll
        for (int d = 0; d < NDMA; d++) {
            int sel = (EPD == 2) ? (lane >> 5) : (lane >> 4);
            int r = nxt[EPD * d + sel];
            const f16* g = xlh + (size_t)r * M + ((lane & (64 / EPD - 1)) << 3);
            dma16h(g, lbase + d * 512);
        }
    };

    loadcols(0);
    issue(0);
    if (nb > 1) loadcols(1);

    for (int k = 0; k < nb; k++) {
        bool more = (k + 1 < nb);
        if (more) {
            issue((k + 1) & 1);
            if (NDMA == 2)
                asm volatile("s_waitcnt vmcnt(2)" ::: "memory");
            else
                asm volatile("s_waitcnt vmcnt(1)" ::: "memory");
        } else {
            asm volatile("s_waitcnt vmcnt(0)" ::: "memory");
        }
        if (k + 2 < nb) loadcols(k + 2);

        const f16* lb = &lds[wv][k & 1][0];
        const int ebase = e0 + k * B;
        f16x4 xv4[B];
        float sc[B];
#pragma unroll
        for (int b = 0; b < B; b++) {
            const f16* rowp = (EPD == 2)
                ? lb + (b >> 1) * 512 + (b & 1) * 256 + lane * 4
                : lb + (b & 3) * 128 + lane * 2;
            if (VPL == 4) {
                xv4[b] = *(const f16x4*)rowp;
            } else {
                f16x2 t = *(const f16x2*)rowp;
                xv4[b].x = t.x; xv4[b].y = t.y;
            }
            float s = 0.f;
#pragma unroll
            for (int p = 0; p < NP; p++) {
                f16x2 xp;
                xp.x = (p == 0) ? xv4[b].x : xv4[b].z;
                xp.y = (p == 0) ? xv4[b].y : xv4[b].w;
                f16x2 t = xp + xr2[p];
                f16x2 lk = __builtin_elementwise_max(t, z2) +
                           ns2 * __builtin_elementwise_min(t, z2);
                s = __builtin_amdgcn_fdot2(lk, at2[p], s, false);
            }
            sc[b] = s;
        }
        constexpr int RED = (H == 4) ? 8 : 32;
#pragma unroll
        for (int off = 1; off <= RED; off <<= 1)
#pragma unroll
            for (int b = 0; b < B; b++) sc[b] += __shfl_xor(sc[b], off, 64);
#pragma unroll
        for (int b = 0; b < B; b++) {
            float w = (ebase + b < e1) ? __expf(sc[b]) : 0.f;
            den += w;
            acc[0] += w * (float)xv4[b].x;
            acc[1] += w * (float)xv4[b].y;
            if (VPL == 4) {
                acc[2] += w * (float)xv4[b].z;
                acc[3] += w * (float)xv4[b].w;
            }
        }
    }

    float inv = 1.0f / den;
    float ov[VPL];
#pragma unroll
    for (int j = 0; j < VPL; j++) {
        int hc = base + j;
        float val = acc[j] * inv + cb[hc];
        val = (val - bn_m[hc]) * bn_g[hc] / sqrtf(bn_v[hc] + BNEPS) + bn_b[hc];
        if (ELU) val = (val > 0.f) ? val : expm1f(val);
        ov[j] = val;
    }
    if (OUTH) {
        f16* op = outh + (size_t)i * M + base;
        if (VPL == 4) {
            f16x4 v; v.x = (f16)ov[0]; v.y = (f16)ov[1];
            v.z = (f16)ov[2]; v.w = (f16)ov[3];
            *(f16x4*)op = v;
        } else {
            f16x2 v; v.x = (f16)ov[0]; v.y = (f16)ov[1];
            *(f16x2*)op = v;
        }
    } else {
        float* op = outf + (size_t)i * M + base;
        if (VPL == 4) {
            float4 v; v.x = ov[0]; v.y = ov[1]; v.z = ov[2]; v.w = ov[3];
            *(float4*)op = v;
        } else {
            float2 v; v.x = ov[0]; v.y = ov[1];
            *(float2*)op = v;
        }
    }
}

// ---------------------------------------------------------------------------
// Graph pooling without atomics (batch[] sorted -> contiguous ranges)
// ---------------------------------------------------------------------------
__device__ __forceinline__ int lower_bound_i(const int* a, int n, int v) {
    int lo = 0, hi = n;
    while (lo < hi) {
        int m = (lo + hi) >> 1;
        if (a[m] < v) lo = m + 1; else hi = m;
    }
    return lo;
}

__global__ __launch_bounds__(512) void pool_kernel(
    const float* __restrict__ h, const int* __restrict__ batch,
    float* __restrict__ sum_out, float* __restrict__ max_out,
    float* __restrict__ cnt, int n) {
    int g = blockIdx.x;
    int tid = threadIdx.x;
    int ch = tid & 127;
    int r = tid >> 7;

    int lo = lower_bound_i(batch, n, g);
    int hi = lower_bound_i(batch, n, g + 1);

    float sum = 0.f, mx = -INFINITY;
    for (int i = lo + r; i < hi; i += 4) {
        float v = h[(size_t)i * 128 + ch];
        sum += v;
        mx = fmaxf(mx, v);
    }
    __shared__ float ssum[512], smax[512];
    ssum[tid] = sum; smax[tid] = mx;
    __syncthreads();
    if (r == 0) {
        sum = ssum[ch] + ssum[128 + ch] + ssum[256 + ch] + ssum[384 + ch];
        mx = fmaxf(fmaxf(smax[ch], smax[128 + ch]),
                   fmaxf(smax[256 + ch], smax[384 + ch]));
        sum_out[g * 128 + ch] = sum;
        max_out[g * 128 + ch] = mx;
        if (ch == 0) cnt[g] = (float)(hi - lo);
    }
}

// ---------------------------------------------------------------------------
// Classifier MLP: one block (128 threads) per graph. 256->128->64->1
// ---------------------------------------------------------------------------
__global__ __launch_bounds__(128) void mlp_kernel(
    const float* __restrict__ sum_in, const float* __restrict__ max_in,
    const float* __restrict__ cnt, const float* __restrict__ cw0,
    const float* __restrict__ cb0, const float* __restrict__ cw1,
    const float* __restrict__ cb1, const float* __restrict__ cw2,
    const float* __restrict__ cb2, float* __restrict__ out) {
    int g = blockIdx.x;
    int t = threadIdx.x;
    __shared__ float z[256];
    __shared__ float z1[128];

    float c = cnt[g];
    float inv = 1.0f / fmaxf(c, 1.0f);
    z[t] = sum_in[g * 128 + t] * inv;
    float mx = max_in[g * 128 + t];
    if (!isfinite(mx)) mx = 0.f;
    z[128 + t] = mx;
    __syncthreads();

    float a = cb0[t];
    for (int k = 0; k < 256; k++) a += z[k] * cw0[k * 128 + t];
    z1[t] = fmaxf(a, 0.f);
    __syncthreads();

    if (t < 64) {
        float b = cb1[t];
        for (int k = 0; k < 128; k++) b += z1[k] * cw1[k * 64 + t];
        float p = fmaxf(b, 0.f) * cw2[t];
#pragma unroll
        for (int off = 32; off >= 1; off >>= 1) p += __shfl_xor(p, off, 64);
        if (t == 0) out[g] = p + cb2[0];
    }
}

// ---------------------------------------------------------------------------
extern "C" void kernel_launch(void* const* d_in, const int* in_sizes, int n_in,
                              void* d_out, int out_size, void* d_ws, size_t ws_size,
                              hipStream_t stream) {
    const float* x = (const float*)d_in[0];
    const int* ei = (const int*)d_in[1];
    const int* batch = (const int*)d_in[2];
    const float* Wl0 = (const float*)d_in[3];
    const float* bl0 = (const float*)d_in[4];
    const float* Wr0 = (const float*)d_in[5];
    const float* br0 = (const float*)d_in[6];
    const float* a0 = (const float*)d_in[7];
    const float* c0 = (const float*)d_in[8];
    const float* Wl1 = (const float*)d_in[9];
    const float* bl1 = (const float*)d_in[10];
    const float* Wr1 = (const float*)d_in[11];
    const float* br1 = (const float*)d_in[12];
    const float* a1 = (const float*)d_in[13];
    const float* c1 = (const float*)d_in[14];
    const float* Wl2 = (const float*)d_in[15];
    const float* bl2 = (const float*)d_in[16];
    const float* Wr2 = (const float*)d_in[17];
    const float* br2 = (const float*)d_in[18];
    const float* a2 = (const float*)d_in[19];
    const float* c2 = (const float*)d_in[20];
    const float* g0 = (const float*)d_in[21];
    const float* be0 = (const float*)d_in[22];
    const float* m0 = (const float*)d_in[23];
    const float* v0 = (const float*)d_in[24];
    const float* g1 = (const float*)d_in[25];
    const float* be1 = (const float*)d_in[26];
    const float* m1 = (const float*)d_in[27];
    const float* v1 = (const float*)d_in[28];
    const float* g2 = (const float*)d_in[29];
    const float* be2 = (const float*)d_in[30];
    const float* m2 = (const float*)d_in[31];
    const float* v2 = (const float*)d_in[32];
    const float* cw0 = (const float*)d_in[33];
    const float* cb0 = (const float*)d_in[34];
    const float* cw1 = (const float*)d_in[35];
    const float* cb1 = (const float*)d_in[36];
    const float* cw2 = (const float*)d_in[37];
    const float* cb2 = (const float*)d_in[38];
    float* out = (float*)d_out;

    const int N = NNODES, E = NEDGES, G = NGRAPH;
    char* ws = (char*)d_ws;
    size_t off = 0;
    auto alloc = [&](size_t bytes) -> void* {
        void* p = ws + off;
        off += (bytes + 255) & ~(size_t)255;
        return p;
    };
    f16* xh = (f16*)alloc((size_t)NPAD * 128 * 2);      // x as fp16
    f16* h16 = (f16*)alloc((size_t)NPAD * 256 * 2);     // inter-layer h fp16
    f16* xlh = (f16*)alloc((size_t)NPAD * 256 * 2);     // gathered operand
    f16* xrh = (f16*)alloc((size_t)NPAD * 256 * 2);     // per-dst operand fp16
    float* h2 = (float*)alloc((size_t)N * 128 * 4);     // L2 agg out (pool in)
    f16* Bp0 = (f16*)alloc((size_t)128 * 512 * 2);
    f16* Bp1 = (f16*)alloc((size_t)256 * 512 * 2);
    f16* Bp2 = (f16*)alloc((size_t)256 * 256 * 2);
    int* deg = (int*)alloc((size_t)N * 4);
    int* row_ptr = (int*)alloc((size_t)(N + 1) * 4);
    int* cursor = (int*)alloc((size_t)N * 4);
    int* col_idx = (int*)alloc((size_t)(E + N) * 4);
    int* bsum = (int*)alloc((size_t)64 * 4);
    float* mean_acc = (float*)alloc((size_t)G * 128 * 4);
    float* gmax_f = (float*)alloc((size_t)G * 128 * 4);
    float* cnt = (float*)alloc((size_t)G * 4);
    (void)ws_size; (void)n_in; (void)in_sizes; (void)out_size;

    hipMemsetAsync(deg, 0, (size_t)N * 4, stream);

    int totE = E + N;
    int ntiles = (N + 1023) / 1024;  // 49
    hist_kernel<<<(totE + 255) / 256, 256, 0, stream>>>(ei, deg, E, N);
    scan1_kernel<<<ntiles, 256, 0, stream>>>(deg, bsum, N);
    scan2_kernel<<<1, 64, 0, stream>>>(bsum, ntiles);
    scan3_kernel<<<ntiles, 256, 0, stream>>>(deg, bsum, row_ptr, cursor, N);
    scatter_kernel<<<(totE + 255) / 256, 256, 0, stream>>>(ei, cursor, col_idx, E, N);
    sortadj_kernel<<<(N + 3) / 4, 256, 0, stream>>>(row_ptr, col_idx, N);

    // one-shot prep: cvt + all 3 weight packs
    int prepN = N * 128 / 4 + 128 * 512 + 256 * 512 + 256 * 256;
    prep_kernel<<<(prepN + 255) / 256, 256, 0, stream>>>(
        x, xh, Wl0, Wr0, Bp0, Wl1, Wr1, Bp1, Wl2, Wr2, Bp2);

    int gblocks = NPAD / 64;              // 782
    int agg_grid = (N + 3) / 4;

    // Layer 0: 128 -> 4x64, ELU(BN(.)), h16 out
    gemm_mfma_kernel<128, 256><<<dim3(gblocks, 2), 256, 0, stream>>>(
        xh, Bp0, bl0, br0, xlh, xrh, N);
    gat_agg_kernel<4, 64, true, true><<<agg_grid, 256, 0, stream>>>(
        xlh, xrh, a0, c0, g0, be0, m0, v0, row_ptr, col_idx, h16, nullptr, N);

    // Layer 1: 256 -> 4x64, ELU(BN(.)), h16 out
    gemm_mfma_kernel<256, 256><<<dim3(gblocks, 2), 256, 0, stream>>>(
        h16, Bp1, bl1, br1, xlh, xrh, N);
    gat_agg_kernel<4, 64, true, true><<<agg_grid, 256, 0, stream>>>(
        xlh, xrh, a1, c1, g1, be1, m1, v1, row_ptr, col_idx, h16, nullptr, N);

    // Layer 2: 256 -> 1x128, BN only, fp32 out for pooling
    gemm_mfma_kernel<256, 128><<<dim3(gblocks, 1), 256, 0, stream>>>(
        h16, Bp2, bl2, br2, xlh, xrh, N);
    gat_agg_kernel<1, 128, false, false><<<agg_grid, 256, 0, stream>>>(
        xlh, xrh, a2, c2, g2, be2, m2, v2, row_ptr, col_idx, nullptr, h2, N);

    pool_kernel<<<G, 512, 0, stream>>>(h2, batch, mean_acc, gmax_f, cnt, N);
    mlp_kernel<<<G, 128, 0, stream>>>(mean_acc, gmax_f, cnt, cw0, cb0, cw1, cb1, cw2, cb2, out);
}